// Round 2
// baseline (598.649 us; speedup 1.0000x reference)
//
#include <hip/hip_runtime.h>

#define BLOCK 256
#define PER_THREAD 8
#define C 128

// Stage 1: per-block partial sums of log(predicts[i, labels[i]]).
// 8 rows per thread -> 8 independent scattered loads in flight per lane.
__global__ __launch_bounds__(BLOCK) void ce_partial_kernel(
    const float* __restrict__ predicts,
    const int* __restrict__ labels,
    float* __restrict__ partial,   // [gridDim.x]
    int n)
{
    const int tid = blockIdx.x * BLOCK + threadIdx.x;
    const int i0 = tid * PER_THREAD;

    float s = 0.0f;
    if (i0 + PER_THREAD <= n) {
        // Two coalesced int4 label loads, then 8 independent gathers (MLP).
        int4 la = *reinterpret_cast<const int4*>(labels + i0);
        int4 lb = *reinterpret_cast<const int4*>(labels + i0 + 4);
        const float* row = predicts + (size_t)i0 * C;
        float p0 = row[0 * C + la.x];
        float p1 = row[1 * C + la.y];
        float p2 = row[2 * C + la.z];
        float p3 = row[3 * C + la.w];
        float p4 = row[4 * C + lb.x];
        float p5 = row[5 * C + lb.y];
        float p6 = row[6 * C + lb.z];
        float p7 = row[7 * C + lb.w];
        s = (__logf(p0) + __logf(p1)) + (__logf(p2) + __logf(p3)) +
            (__logf(p4) + __logf(p5)) + (__logf(p6) + __logf(p7));
    } else {
        for (int i = i0; i < n; ++i)
            s += __logf(predicts[(size_t)i * C + labels[i]]);
    }

    // Wave (64-lane) shuffle reduction.
    #pragma unroll
    for (int off = 32; off > 0; off >>= 1)
        s += __shfl_down(s, off, 64);

    // Cross-wave reduction via LDS (BLOCK/64 = 4 waves).
    __shared__ float wave_sums[BLOCK / 64];
    const int lane = threadIdx.x & 63;
    const int wv   = threadIdx.x >> 6;
    if (lane == 0) wave_sums[wv] = s;
    __syncthreads();

    if (threadIdx.x == 0) {
        partial[blockIdx.x] =
            wave_sums[0] + wave_sums[1] + wave_sums[2] + wave_sums[3];
    }
}

// Stage 2: reduce the per-block partials; single plain store to out.
// No memset / atomics needed: out is written unconditionally.
__global__ __launch_bounds__(256) void ce_final_kernel(
    const float* __restrict__ partial, int nparts,
    float neg_inv_n, float* __restrict__ out)
{
    float s = 0.0f;
    for (int i = threadIdx.x; i < nparts; i += 256)
        s += partial[i];

    #pragma unroll
    for (int off = 32; off > 0; off >>= 1)
        s += __shfl_down(s, off, 64);

    __shared__ float wave_sums[4];
    const int lane = threadIdx.x & 63;
    const int wv   = threadIdx.x >> 6;
    if (lane == 0) wave_sums[wv] = s;
    __syncthreads();

    if (threadIdx.x == 0) {
        float total = wave_sums[0] + wave_sums[1] + wave_sums[2] + wave_sums[3];
        out[0] = total * neg_inv_n;   // loss = -(1/N) * sum(log p)
    }
}

extern "C" void kernel_launch(void* const* d_in, const int* in_sizes, int n_in,
                              void* d_out, int out_size, void* d_ws, size_t ws_size,
                              hipStream_t stream) {
    const float* predicts = (const float*)d_in[0];
    const int*   labels   = (const int*)d_in[1];
    float*       out      = (float*)d_out;
    float*       partial  = (float*)d_ws;
    const int n = in_sizes[1];  // N rows

    const int per_block = BLOCK * PER_THREAD;          // 2048
    const int grid = (n + per_block - 1) / per_block;  // 512 for N=1M

    ce_partial_kernel<<<grid, BLOCK, 0, stream>>>(predicts, labels, partial, n);
    ce_final_kernel<<<1, 256, 0, stream>>>(partial, grid, -1.0f / (float)n, out);
}